// Round 7
// baseline (199.533 us; speedup 1.0000x reference)
//
#include <hip/hip_runtime.h>
#include <hip/hip_bf16.h>
#include <math.h>

// SkipGRU on MI355X, round 7: fix the grid-barrier RMW-spin convoy (round 6's
// 109us chain): per-step padded counters, arrival=fetch_add, wait=relaxed
// atomic LOAD spin + s_sleep. h carried in registers (wave's output patch at
// step c IS its hold patch at c+1); MX chunk c+1 prefetched before the sync.
//
// Only chain j=23 contributes to outputs[:, -1, :] (t=191 = chunk 7 lane 23):
// 8 sequential GRU steps over x[:, c*24+23, :], h[256,512].
//
// mfma_f32_16x16x32_bf16 layouts (learn_hip m89-verified):
//   A: lane l holds A[l&15][(l>>4)*8 + j]
//   B: lane l holds B[(l>>4)*8 + j][l&15]  (B^T row-major -> contiguous load)
//   D: lane l reg q -> row (l>>4)*4+q, col l&15

typedef float f32x4 __attribute__((ext_vector_type(4)));
typedef short short8 __attribute__((ext_vector_type(8)));

#define BB 256
#define UU 512
#define KK 512
#define N3 1536
#define NWG 128   // chain workgroups (<= 256 CUs -> co-resident)

__device__ __forceinline__ float sigmoidf_(float s) {
    return 1.0f / (1.0f + __expf(-s));
}

// W[R][C] f32  ->  Wt[C][R] bf16   (LDS-tiled transpose)
__global__ __launch_bounds__(256)
void transpose_bf16(const float* __restrict__ W, __hip_bfloat16* __restrict__ Wt,
                    int R, int C)
{
    __shared__ float tile[32][33];
    const int x = threadIdx.x;          // 0..31
    const int y = threadIdx.y;          // 0..7
    const int c0 = blockIdx.x * 32;
    const int r0 = blockIdx.y * 32;
    #pragma unroll
    for (int i = 0; i < 32; i += 8)
        tile[y + i][x] = W[(long)(r0 + y + i) * C + c0 + x];
    __syncthreads();
    #pragma unroll
    for (int i = 0; i < 32; i += 8)
        Wt[(long)(c0 + y + i) * R + r0 + x] = __float2bfloat16(tile[x][y + i]);
}

// Gather the 8 needed timesteps of x and convert to bf16: Xb[c*256+b][k]
__global__ __launch_bounds__(256)
void convert_x(const float* __restrict__ x, __hip_bfloat16* __restrict__ Xb)
{
    const int idx = blockIdx.x * 256 + threadIdx.x;   // one thread per 8 elems
    const int e = idx * 8;
    const int m = e >> 9;              // 0..2047 = c*256+b
    const int kk = e & 511;
    const int b = m & 255, c = m >> 8;
    const float* src = x + (long)b * (192 * 512) + (long)(c * 24 + 23) * 512 + kk;
    float4 v0 = *(const float4*)src;
    float4 v1 = *(const float4*)(src + 4);
    __hip_bfloat16* dst = Xb + (long)m * 512 + kk;
    dst[0] = __float2bfloat16(v0.x);
    dst[1] = __float2bfloat16(v0.y);
    dst[2] = __float2bfloat16(v0.z);
    dst[3] = __float2bfloat16(v0.w);
    dst[4] = __float2bfloat16(v1.x);
    dst[5] = __float2bfloat16(v1.y);
    dst[6] = __float2bfloat16(v1.z);
    dst[7] = __float2bfloat16(v1.w);
}

// MX = A @ Kt^T + bias:  A[2048][512] bf16, Kt[1536][512] bf16 (=W^T), out f32.
__global__ __launch_bounds__(256)
void gemm_mx(const __hip_bfloat16* __restrict__ A,
             const __hip_bfloat16* __restrict__ Bt,
             const float* __restrict__ bias,
             float* __restrict__ C)
{
    const int tid = threadIdx.x;
    const int lane = tid & 63;
    const int wid = tid >> 6;                    // 0..3
    const int m0 = blockIdx.y * 64 + wid * 16;
    const int n0 = blockIdx.x * 64;
    const int lr = lane & 15;
    const int lk = (lane >> 4) * 8;

    const short8* ap = (const short8*)(A + (long)(m0 + lr) * KK + lk);
    const short8* bp = (const short8*)(Bt + (long)(n0 + lr) * KK + lk);

    f32x4 acc[4] = {{0.f,0.f,0.f,0.f},{0.f,0.f,0.f,0.f},
                    {0.f,0.f,0.f,0.f},{0.f,0.f,0.f,0.f}};
    #pragma unroll
    for (int k = 0; k < 16; ++k) {               // k0 = 32*k
        short8 a = ap[k * 4];
        #pragma unroll
        for (int t = 0; t < 4; ++t) {
            short8 b = bp[t * 1024 + k * 4];     // +16 rows = 16*512/8 short8
            acc[t] = __builtin_amdgcn_mfma_f32_16x16x32_bf16(a, b, acc[t], 0, 0, 0);
        }
    }
    const int row = (lane >> 4) * 4;
    #pragma unroll
    for (int t = 0; t < 4; ++t) {
        const int u = n0 + t * 16 + lr;
        const float bi = bias[u];
        #pragma unroll
        for (int q = 0; q < 4; ++q)
            C[(long)(m0 + row + q) * N3 + u] = acc[t][q] + bi;
    }
}

// Zero the 7 padded barrier counters (one per inter-step sync) each replay.
__global__ void bar_init(unsigned* bar)
{
    if (threadIdx.x < 7 * 16) bar[threadIdx.x] = 0u;
}

// Arrival: one fetch_add. Wait: relaxed atomic LOAD spin (no RMW convoy) +
// s_sleep. Fencing identical to round 6 (validated cross-XCD).
__device__ __forceinline__ void grid_sync_(unsigned* cnt)
{
    __syncthreads();
    if (threadIdx.x == 0) {
        __threadfence();
        unsigned prev = __hip_atomic_fetch_add(cnt, 1u, __ATOMIC_RELEASE,
                                               __HIP_MEMORY_SCOPE_AGENT);
        if (prev != NWG - 1u) {
            while (__hip_atomic_load(cnt, __ATOMIC_ACQUIRE,
                                     __HIP_MEMORY_SCOPE_AGENT) < NWG)
                __builtin_amdgcn_s_sleep(2);
        }
        __threadfence();
    }
    __syncthreads();
}

// Persistent 8-step GRU chain. 128 WGs x 256 thr; wave owns one 16x16 (m,u)
// patch across all 3 gates and ALL 8 steps; h carried in registers for the
// own patch; bf16 h double-buffered in global for cross-WG A-fragments.
__global__ __launch_bounds__(256)
void gru_chain(const __hip_bfloat16* __restrict__ Rt,   // [1536][512] bf16
               const float* __restrict__ rbias,         // [1536]
               const float* __restrict__ MX,            // [8][256][1536] f32
               __hip_bfloat16* __restrict__ hbA,
               __hip_bfloat16* __restrict__ hbB,
               float* __restrict__ out,                 // [256][512] f32
               unsigned* __restrict__ bar)
{
    const int tid = threadIdx.x;
    const int lane = tid & 63;
    const int wid = tid >> 6;
    const int bx = blockIdx.x & 15;       // n block (16 x 32 cols)
    const int by = blockIdx.x >> 4;       // m block (8 x 32 rows)
    const int wy = wid >> 1, wx = wid & 1;
    const int m0 = by * 32 + wy * 16;
    const int n0 = bx * 32 + wx * 16;
    const int lr = lane & 15;
    const int lk = (lane >> 4) * 8;
    const int row = (lane >> 4) * 4;
    const int u = n0 + lr;

    const short8* bp = (const short8*)(Rt + (long)(n0 + lr) * KK + lk);
    const float rbz = rbias[u];
    const float rbr = rbias[u + UU];
    const float rbh = rbias[u + 2 * UU];

    // MX chunk 0 + register-carried h (own patch).
    float mxz[4], mxr[4], mxh[4], hreg[4];
    #pragma unroll
    for (int q = 0; q < 4; ++q) {
        const float* mx = MX + (long)(m0 + row + q) * N3 + u;
        mxz[q] = mx[0];
        mxr[q] = mx[UU];
        mxh[q] = mx[2 * UU];
        hreg[q] = 0.0f;
    }

    #pragma unroll 1
    for (int c = 0; c < 8; ++c) {
        const __hip_bfloat16* hb_in = (c & 1) ? hbB : hbA;
        __hip_bfloat16*       hb_o  = (c & 1) ? hbA : hbB;

        f32x4 az = {0.f,0.f,0.f,0.f}, ag = {0.f,0.f,0.f,0.f}, ah = {0.f,0.f,0.f,0.f};
        if (c > 0) {
            const short8* ap = (const short8*)(hb_in + (long)(m0 + lr) * KK + lk);
            short8 A[16];
            #pragma unroll
            for (int k = 0; k < 16; ++k) A[k] = ap[k * 4];
            #pragma unroll
            for (int k = 0; k < 16; ++k) {
                az = __builtin_amdgcn_mfma_f32_16x16x32_bf16(A[k], bp[k * 4],         az, 0, 0, 0);
                ag = __builtin_amdgcn_mfma_f32_16x16x32_bf16(A[k], bp[32768 + k * 4], ag, 0, 0, 0);
                ah = __builtin_amdgcn_mfma_f32_16x16x32_bf16(A[k], bp[65536 + k * 4], ah, 0, 0, 0);
            }
        }

        #pragma unroll
        for (int q = 0; q < 4; ++q) {
            const float z = sigmoidf_(mxz[q] + az[q] + rbz);
            const float r = sigmoidf_(mxr[q] + ag[q] + rbr);
            const float cand = mxh[q] + r * (ah[q] + rbh);   // reset_after
            const float hh = fmaxf(cand, 0.0f);              // relu
            hreg[q] = z * hreg[q] + (1.0f - z) * hh;
        }

        if (c < 7) {
            #pragma unroll
            for (int q = 0; q < 4; ++q)
                hb_o[(long)(m0 + row + q) * UU + u] = __float2bfloat16(hreg[q]);
            // Prefetch next MX chunk BEFORE the sync (latency hides under wait).
            const float* MXn = MX + (long)(c + 1) * BB * N3;
            #pragma unroll
            for (int q = 0; q < 4; ++q) {
                const float* mx = MXn + (long)(m0 + row + q) * N3 + u;
                mxz[q] = mx[0];
                mxr[q] = mx[UU];
                mxh[q] = mx[2 * UU];
            }
            grid_sync_(&bar[c * 16]);
        } else {
            #pragma unroll
            for (int q = 0; q < 4; ++q)
                out[(long)(m0 + row + q) * UU + u] = hreg[q];
        }
    }
}

extern "C" void kernel_launch(void* const* d_in, const int* in_sizes, int n_in,
                              void* d_out, int out_size, void* d_ws, size_t ws_size,
                              hipStream_t stream)
{
    const float* x     = (const float*)d_in[0];   // [256,192,512]
    const float* ker   = (const float*)d_in[1];   // [512,1536]
    const float* rker  = (const float*)d_in[2];   // [512,1536]
    const float* ibias = (const float*)d_in[3];   // [1536]
    const float* rbias = (const float*)d_in[4];   // [1536]
    float* out = (float*)d_out;                   // [256,512]

    char* ws = (char*)d_ws;
    float*          MX   = (float*)ws;                            // 12,582,912 B
    __hip_bfloat16* Xb   = (__hip_bfloat16*)(ws + 12582912);      //  2,097,152 B
    __hip_bfloat16* Kt   = (__hip_bfloat16*)(ws + 14680064);      //  1,572,864 B
    __hip_bfloat16* Rt   = (__hip_bfloat16*)(ws + 16252928);      //  1,572,864 B
    __hip_bfloat16* hbA  = (__hip_bfloat16*)(ws + 17825792);      //    262,144 B
    __hip_bfloat16* hbB  = (__hip_bfloat16*)(ws + 18087936);      //    262,144 B
    unsigned*       bar  = (unsigned*)(ws + 18350080);            //        448 B

    // Phase 0: weight transposes + x gather/convert + barrier init
    transpose_bf16<<<dim3(48, 16), dim3(32, 8), 0, stream>>>(ker,  Kt, 512, 1536);
    transpose_bf16<<<dim3(48, 16), dim3(32, 8), 0, stream>>>(rker, Rt, 512, 1536);
    convert_x<<<512, 256, 0, stream>>>(x, Xb);
    bar_init<<<1, 128, 0, stream>>>(bar);

    // Phase 1: MX = Xsel @ kernel + input_bias
    gemm_mx<<<dim3(N3 / 64, 2048 / 64), 256, 0, stream>>>(Xb, Kt, ibias, MX);

    // Phase 2: all 8 GRU steps in one persistent kernel.
    gru_chain<<<NWG, 256, 0, stream>>>(Rt, rbias, MX, hbA, hbB, out, bar);
}

// Round 8
// 157.171 us; speedup vs baseline: 1.2695x; 1.2695x over previous
//
#include <hip/hip_runtime.h>
#include <hip/hip_bf16.h>
#include <math.h>

// SkipGRU on MI355X, round 8: persistent chain with GROUP-LOCAL barriers.
// Round 6/7 lesson: grid-wide barriers with agent-scope acquire SPINS
// invalidate L2 on every poll iteration (cross-XCD coherence) -> 15-20us per
// barrier. Fix: (a) sync only the 16 WGs of a row-group (the true dependency
// domain: row-block m's h is produced and consumed by the same 16 WGs);
// (b) spin on RELAXED atomic loads, single acquire fence on exit.
// Group id = blockIdx&7 -> members land on the same XCD under round-robin
// dispatch (perf heuristic only; fences keep it correct regardless).
//
// Only chain j=23 contributes to outputs[:, -1, :] (t=191 = chunk 7 lane 23):
// 8 sequential GRU steps over x[:, c*24+23, :], h[256,512].
//
// mfma_f32_16x16x32_bf16 layouts (learn_hip m89-verified):
//   A: lane l holds A[l&15][(l>>4)*8 + j]
//   B: lane l holds B[(l>>4)*8 + j][l&15]  (B^T row-major -> contiguous load)
//   D: lane l reg q -> row (l>>4)*4+q, col l&15

typedef float f32x4 __attribute__((ext_vector_type(4)));
typedef short short8 __attribute__((ext_vector_type(8)));

#define BB 256
#define UU 512
#define KK 512
#define N3 1536
#define NWG 128   // 8 row-groups x 16 column-WGs; <= 256 CUs -> co-resident
#define GWG 16    // WGs per row-group (the sync domain)

__device__ __forceinline__ float sigmoidf_(float s) {
    return 1.0f / (1.0f + __expf(-s));
}

// W[R][C] f32  ->  Wt[C][R] bf16   (LDS-tiled transpose)
__global__ __launch_bounds__(256)
void transpose_bf16(const float* __restrict__ W, __hip_bfloat16* __restrict__ Wt,
                    int R, int C)
{
    __shared__ float tile[32][33];
    const int x = threadIdx.x;          // 0..31
    const int y = threadIdx.y;          // 0..7
    const int c0 = blockIdx.x * 32;
    const int r0 = blockIdx.y * 32;
    #pragma unroll
    for (int i = 0; i < 32; i += 8)
        tile[y + i][x] = W[(long)(r0 + y + i) * C + c0 + x];
    __syncthreads();
    #pragma unroll
    for (int i = 0; i < 32; i += 8)
        Wt[(long)(c0 + y + i) * R + r0 + x] = __float2bfloat16(tile[x][y + i]);
}

// Gather the 8 needed timesteps of x and convert to bf16: Xb[c*256+b][k]
__global__ __launch_bounds__(256)
void convert_x(const float* __restrict__ x, __hip_bfloat16* __restrict__ Xb)
{
    const int idx = blockIdx.x * 256 + threadIdx.x;   // one thread per 8 elems
    const int e = idx * 8;
    const int m = e >> 9;              // 0..2047 = c*256+b
    const int kk = e & 511;
    const int b = m & 255, c = m >> 8;
    const float* src = x + (long)b * (192 * 512) + (long)(c * 24 + 23) * 512 + kk;
    float4 v0 = *(const float4*)src;
    float4 v1 = *(const float4*)(src + 4);
    __hip_bfloat16* dst = Xb + (long)m * 512 + kk;
    dst[0] = __float2bfloat16(v0.x);
    dst[1] = __float2bfloat16(v0.y);
    dst[2] = __float2bfloat16(v0.z);
    dst[3] = __float2bfloat16(v0.w);
    dst[4] = __float2bfloat16(v1.x);
    dst[5] = __float2bfloat16(v1.y);
    dst[6] = __float2bfloat16(v1.z);
    dst[7] = __float2bfloat16(v1.w);
}

// MX = A @ Kt^T + bias:  A[2048][512] bf16, Kt[1536][512] bf16 (=W^T), out f32.
__global__ __launch_bounds__(256)
void gemm_mx(const __hip_bfloat16* __restrict__ A,
             const __hip_bfloat16* __restrict__ Bt,
             const float* __restrict__ bias,
             float* __restrict__ C)
{
    const int tid = threadIdx.x;
    const int lane = tid & 63;
    const int wid = tid >> 6;                    // 0..3
    const int m0 = blockIdx.y * 64 + wid * 16;
    const int n0 = blockIdx.x * 64;
    const int lr = lane & 15;
    const int lk = (lane >> 4) * 8;

    const short8* ap = (const short8*)(A + (long)(m0 + lr) * KK + lk);
    const short8* bp = (const short8*)(Bt + (long)(n0 + lr) * KK + lk);

    f32x4 acc[4] = {{0.f,0.f,0.f,0.f},{0.f,0.f,0.f,0.f},
                    {0.f,0.f,0.f,0.f},{0.f,0.f,0.f,0.f}};
    #pragma unroll
    for (int k = 0; k < 16; ++k) {               // k0 = 32*k
        short8 a = ap[k * 4];
        #pragma unroll
        for (int t = 0; t < 4; ++t) {
            short8 b = bp[t * 1024 + k * 4];     // +16 rows = 16*512/8 short8
            acc[t] = __builtin_amdgcn_mfma_f32_16x16x32_bf16(a, b, acc[t], 0, 0, 0);
        }
    }
    const int row = (lane >> 4) * 4;
    #pragma unroll
    for (int t = 0; t < 4; ++t) {
        const int u = n0 + t * 16 + lr;
        const float bi = bias[u];
        #pragma unroll
        for (int q = 0; q < 4; ++q)
            C[(long)(m0 + row + q) * N3 + u] = acc[t][q] + bi;
    }
}

// Zero the 7*8 padded group-barrier counters each replay.
__global__ void bar_init(unsigned* bar)
{
    const int i = blockIdx.x * 256 + threadIdx.x;
    if (i < 7 * 8 * 16) bar[i] = 0u;
}

// Group barrier (16 WGs). Arrival: release fence + one RELAXED fetch_add.
// Wait: RELAXED load spin (coherence-point read of ONE line, no cache
// invalidate) + s_sleep. Exit: one acquire fence.
__device__ __forceinline__ void group_sync_(unsigned* cnt)
{
    __syncthreads();
    if (threadIdx.x == 0) {
        __threadfence();   // release: h stores visible before arrival
        __hip_atomic_fetch_add(cnt, 1u, __ATOMIC_RELAXED,
                               __HIP_MEMORY_SCOPE_AGENT);
        while (__hip_atomic_load(cnt, __ATOMIC_RELAXED,
                                 __HIP_MEMORY_SCOPE_AGENT) < (unsigned)GWG)
            __builtin_amdgcn_s_sleep(4);
        __threadfence();   // acquire: see other WGs' h stores
    }
    __syncthreads();
}

// Persistent 8-step GRU chain. 8 row-groups x 16 col-WGs x 256 thr.
// Group g (= blockIdx&7) owns rows [g*32, g*32+32); its 16 WGs cover all 512
// cols; h exchange + sync stay within the group. h carried in registers for
// the own patch; bf16 h double-buffered in global for cross-WG A-fragments.
__global__ __launch_bounds__(256)
void gru_chain(const __hip_bfloat16* __restrict__ Rt,   // [1536][512] bf16
               const float* __restrict__ rbias,         // [1536]
               const float* __restrict__ MX,            // [8][256][1536] f32
               __hip_bfloat16* __restrict__ hbA,
               __hip_bfloat16* __restrict__ hbB,
               float* __restrict__ out,                 // [256][512] f32
               unsigned* __restrict__ bar)
{
    const int tid = threadIdx.x;
    const int lane = tid & 63;
    const int wid = tid >> 6;
    const int by = blockIdx.x & 7;        // row-group (same-XCD under RR)
    const int bx = blockIdx.x >> 3;       // column WG within group (0..15)
    const int wy = wid >> 1, wx = wid & 1;
    const int m0 = by * 32 + wy * 16;
    const int n0 = bx * 32 + wx * 16;
    const int lr = lane & 15;
    const int lk = (lane >> 4) * 8;
    const int row = (lane >> 4) * 4;
    const int u = n0 + lr;

    const short8* bp = (const short8*)(Rt + (long)(n0 + lr) * KK + lk);
    const float rbz = rbias[u];
    const float rbr = rbias[u + UU];
    const float rbh = rbias[u + 2 * UU];

    // MX chunk 0 + register-carried h (own patch).
    float mxz[4], mxr[4], mxh[4], hreg[4];
    #pragma unroll
    for (int q = 0; q < 4; ++q) {
        const float* mx = MX + (long)(m0 + row + q) * N3 + u;
        mxz[q] = mx[0];
        mxr[q] = mx[UU];
        mxh[q] = mx[2 * UU];
        hreg[q] = 0.0f;
    }

    #pragma unroll 1
    for (int c = 0; c < 8; ++c) {
        const __hip_bfloat16* hb_in = (c & 1) ? hbB : hbA;
        __hip_bfloat16*       hb_o  = (c & 1) ? hbA : hbB;

        f32x4 az = {0.f,0.f,0.f,0.f}, ag = {0.f,0.f,0.f,0.f}, ah = {0.f,0.f,0.f,0.f};
        if (c > 0) {
            const short8* ap = (const short8*)(hb_in + (long)(m0 + lr) * KK + lk);
            short8 A[16];
            #pragma unroll
            for (int k = 0; k < 16; ++k) A[k] = ap[k * 4];
            #pragma unroll
            for (int k = 0; k < 16; ++k) {
                az = __builtin_amdgcn_mfma_f32_16x16x32_bf16(A[k], bp[k * 4],         az, 0, 0, 0);
                ag = __builtin_amdgcn_mfma_f32_16x16x32_bf16(A[k], bp[32768 + k * 4], ag, 0, 0, 0);
                ah = __builtin_amdgcn_mfma_f32_16x16x32_bf16(A[k], bp[65536 + k * 4], ah, 0, 0, 0);
            }
        }

        #pragma unroll
        for (int q = 0; q < 4; ++q) {
            const float z = sigmoidf_(mxz[q] + az[q] + rbz);
            const float r = sigmoidf_(mxr[q] + ag[q] + rbr);
            const float cand = mxh[q] + r * (ah[q] + rbh);   // reset_after
            const float hh = fmaxf(cand, 0.0f);              // relu
            hreg[q] = z * hreg[q] + (1.0f - z) * hh;
        }

        if (c < 7) {
            #pragma unroll
            for (int q = 0; q < 4; ++q)
                hb_o[(long)(m0 + row + q) * UU + u] = __float2bfloat16(hreg[q]);
            // Prefetch next MX chunk BEFORE the sync (latency hides under wait).
            const float* MXn = MX + (long)(c + 1) * BB * N3;
            #pragma unroll
            for (int q = 0; q < 4; ++q) {
                const float* mx = MXn + (long)(m0 + row + q) * N3 + u;
                mxz[q] = mx[0];
                mxr[q] = mx[UU];
                mxh[q] = mx[2 * UU];
            }
            group_sync_(&bar[(c * 8 + by) * 16]);
        } else {
            #pragma unroll
            for (int q = 0; q < 4; ++q)
                out[(long)(m0 + row + q) * UU + u] = hreg[q];
        }
    }
}

extern "C" void kernel_launch(void* const* d_in, const int* in_sizes, int n_in,
                              void* d_out, int out_size, void* d_ws, size_t ws_size,
                              hipStream_t stream)
{
    const float* x     = (const float*)d_in[0];   // [256,192,512]
    const float* ker   = (const float*)d_in[1];   // [512,1536]
    const float* rker  = (const float*)d_in[2];   // [512,1536]
    const float* ibias = (const float*)d_in[3];   // [1536]
    const float* rbias = (const float*)d_in[4];   // [1536]
    float* out = (float*)d_out;                   // [256,512]

    char* ws = (char*)d_ws;
    float*          MX   = (float*)ws;                            // 12,582,912 B
    __hip_bfloat16* Xb   = (__hip_bfloat16*)(ws + 12582912);      //  2,097,152 B
    __hip_bfloat16* Kt   = (__hip_bfloat16*)(ws + 14680064);      //  1,572,864 B
    __hip_bfloat16* Rt   = (__hip_bfloat16*)(ws + 16252928);      //  1,572,864 B
    __hip_bfloat16* hbA  = (__hip_bfloat16*)(ws + 17825792);      //    262,144 B
    __hip_bfloat16* hbB  = (__hip_bfloat16*)(ws + 18087936);      //    262,144 B
    unsigned*       bar  = (unsigned*)(ws + 18350080);            //      3,584 B

    // Phase 0: weight transposes + x gather/convert + barrier init
    transpose_bf16<<<dim3(48, 16), dim3(32, 8), 0, stream>>>(ker,  Kt, 512, 1536);
    transpose_bf16<<<dim3(48, 16), dim3(32, 8), 0, stream>>>(rker, Rt, 512, 1536);
    convert_x<<<512, 256, 0, stream>>>(x, Xb);
    bar_init<<<4, 256, 0, stream>>>(bar);

    // Phase 1: MX = Xsel @ kernel + input_bias
    gemm_mx<<<dim3(N3 / 64, 2048 / 64), 256, 0, stream>>>(Xb, Kt, ibias, MX);

    // Phase 2: all 8 GRU steps in one persistent kernel (group-local sync).
    gru_chain<<<NWG, 256, 0, stream>>>(Rt, rbias, MX, hbA, hbB, out, bar);
}

// Round 9
// 112.419 us; speedup vs baseline: 1.7749x; 1.3981x over previous
//
#include <hip/hip_runtime.h>
#include <hip/hip_bf16.h>
#include <math.h>

// SkipGRU on MI355X, round 9: revert to the r5 multi-kernel graph (known-good
// 114.9us; three persistent-kernel attempts all lost to it), and fix the step
// kernel's REAL bottleneck: VGPR-starved load serialization. r8's chain showed
// VGPR_Count=88 for a body needing ~260 regs of in-flight fragments -> the
// compiler chunked the 64 independent L2 loads into ~5-fragment groups with
// vmcnt waits between, at 1 wave/SIMD (no TLP). Fix: __launch_bounds__(256,1)
// (full VGPR budget; occupancy 1 wave/SIMD is all we get anyway at 128 WGs)
// + explicit straight-line A[16]/B[3][16] preload, fully unrolled.
//
// Only chain j=23 contributes to outputs[:, -1, :] (t=191 = chunk 7 lane 23):
// 8 sequential GRU steps over x[:, c*24+23, :], h[256,512]. Rows are batch-
// independent; cross-WG coupling is only "tile (m,u) needs all cols of h rows
// m" -> kernel-launch boundaries are the cheapest correct sync measured.
//
// mfma_f32_16x16x32_bf16 layouts (learn_hip m89-verified):
//   A: lane l holds A[l&15][(l>>4)*8 + j]
//   B: lane l holds B[(l>>4)*8 + j][l&15]  (B^T row-major -> contiguous load)
//   D: lane l reg q -> row (l>>4)*4+q, col l&15

typedef float f32x4 __attribute__((ext_vector_type(4)));
typedef short short8 __attribute__((ext_vector_type(8)));

#define BB 256
#define UU 512
#define KK 512
#define N3 1536

__device__ __forceinline__ float sigmoidf_(float s) {
    return 1.0f / (1.0f + __expf(-s));
}

// W[R][C] f32  ->  Wt[C][R] bf16   (LDS-tiled transpose)
__global__ __launch_bounds__(256)
void transpose_bf16(const float* __restrict__ W, __hip_bfloat16* __restrict__ Wt,
                    int R, int C)
{
    __shared__ float tile[32][33];
    const int x = threadIdx.x;          // 0..31
    const int y = threadIdx.y;          // 0..7
    const int c0 = blockIdx.x * 32;
    const int r0 = blockIdx.y * 32;
    #pragma unroll
    for (int i = 0; i < 32; i += 8)
        tile[y + i][x] = W[(long)(r0 + y + i) * C + c0 + x];
    __syncthreads();
    #pragma unroll
    for (int i = 0; i < 32; i += 8)
        Wt[(long)(c0 + y + i) * R + r0 + x] = __float2bfloat16(tile[x][y + i]);
}

// Gather the 8 needed timesteps of x and convert to bf16: Xb[c*256+b][k]
__global__ __launch_bounds__(256)
void convert_x(const float* __restrict__ x, __hip_bfloat16* __restrict__ Xb)
{
    const int idx = blockIdx.x * 256 + threadIdx.x;   // one thread per 8 elems
    const int e = idx * 8;
    const int m = e >> 9;              // 0..2047 = c*256+b
    const int kk = e & 511;
    const int b = m & 255, c = m >> 8;
    const float* src = x + (long)b * (192 * 512) + (long)(c * 24 + 23) * 512 + kk;
    float4 v0 = *(const float4*)src;
    float4 v1 = *(const float4*)(src + 4);
    __hip_bfloat16* dst = Xb + (long)m * 512 + kk;
    dst[0] = __float2bfloat16(v0.x);
    dst[1] = __float2bfloat16(v0.y);
    dst[2] = __float2bfloat16(v0.z);
    dst[3] = __float2bfloat16(v0.w);
    dst[4] = __float2bfloat16(v1.x);
    dst[5] = __float2bfloat16(v1.y);
    dst[6] = __float2bfloat16(v1.z);
    dst[7] = __float2bfloat16(v1.w);
}

// MX = A @ Kt^T + bias:  A[2048][512] bf16, Kt[1536][512] bf16 (=W^T), out f32.
__global__ __launch_bounds__(256)
void gemm_mx(const __hip_bfloat16* __restrict__ A,
             const __hip_bfloat16* __restrict__ Bt,
             const float* __restrict__ bias,
             float* __restrict__ C)
{
    const int tid = threadIdx.x;
    const int lane = tid & 63;
    const int wid = tid >> 6;                    // 0..3
    const int m0 = blockIdx.y * 64 + wid * 16;
    const int n0 = blockIdx.x * 64;
    const int lr = lane & 15;
    const int lk = (lane >> 4) * 8;

    const short8* ap = (const short8*)(A + (long)(m0 + lr) * KK + lk);
    const short8* bp = (const short8*)(Bt + (long)(n0 + lr) * KK + lk);

    f32x4 acc[4] = {{0.f,0.f,0.f,0.f},{0.f,0.f,0.f,0.f},
                    {0.f,0.f,0.f,0.f},{0.f,0.f,0.f,0.f}};
    #pragma unroll
    for (int k = 0; k < 16; ++k) {               // k0 = 32*k
        short8 a = ap[k * 4];
        #pragma unroll
        for (int t = 0; t < 4; ++t) {
            short8 b = bp[t * 1024 + k * 4];     // +16 rows = 16*512/8 short8
            acc[t] = __builtin_amdgcn_mfma_f32_16x16x32_bf16(a, b, acc[t], 0, 0, 0);
        }
    }
    const int row = (lane >> 4) * 4;
    #pragma unroll
    for (int t = 0; t < 4; ++t) {
        const int u = n0 + t * 16 + lr;
        const float bi = bias[u];
        #pragma unroll
        for (int q = 0; q < 4; ++q)
            C[(long)(m0 + row + q) * N3 + u] = acc[t][q] + bi;
    }
}

// Step 0 (h==0): mi = rbias, so pure elementwise from MX chunk 0.
__global__ __launch_bounds__(256)
void gru_step0(const float* __restrict__ MX0,         // [256][1536] f32
               const float* __restrict__ rbias,       // [1536]
               float* __restrict__ hf_out,            // [256][512] f32
               __hip_bfloat16* __restrict__ hbf_out)  // [256][512] bf16
{
    const int idx = blockIdx.x * 256 + threadIdx.x;   // b*512 + u
    const int b = idx >> 9;
    const int u = idx & 511;
    const float* mx = MX0 + (long)b * N3;
    const float z = sigmoidf_(mx[u]          + rbias[u]);
    const float r = sigmoidf_(mx[u + UU]     + rbias[u + UU]);
    const float cand = mx[u + 2 * UU] + r * rbias[u + 2 * UU];
    const float hh = fmaxf(cand, 0.0f);
    const float hn = (1.0f - z) * hh;
    hf_out[idx] = hn;
    hbf_out[idx] = __float2bfloat16(hn);
}

// One fused GRU step: MI = h @ R + rbias (3 gates), then elementwise update.
// Wave owns one 16x16 (m,u) patch across ALL 3 gates. Straight-line preload
// of all fragments; __launch_bounds__(256,1) unlocks the full VGPR budget so
// every load issues before the first vmcnt wait.
__global__ __launch_bounds__(256, 1)
void gru_step(const __hip_bfloat16* __restrict__ hbf,  // [256][512] bf16
              const float* __restrict__ hf,            // [256][512] f32
              const __hip_bfloat16* __restrict__ Rt,   // [1536][512] bf16 (R^T)
              const float* __restrict__ rbias,         // [1536]
              const float* __restrict__ MXc,           // [256][1536] f32
              float* __restrict__ hf_out,              // [256][512] f32
              __hip_bfloat16* __restrict__ hbf_out)    // [256][512] bf16
{
    const int tid = threadIdx.x;
    const int lane = tid & 63;
    const int wid = tid >> 6;
    const int wy = wid >> 1, wx = wid & 1;
    const int m0 = blockIdx.y * 32 + wy * 16;
    const int n0 = blockIdx.x * 32 + wx * 16;
    const int lr = lane & 15;
    const int lk = (lane >> 4) * 8;
    const int row = (lane >> 4) * 4;
    const int u = n0 + lr;

    const short8* ap = (const short8*)(hbf + (long)(m0 + lr) * KK + lk);
    const short8* bp = (const short8*)(Rt + (long)(n0 + lr) * KK + lk);

    // Straight-line preload: 16 A + 48 B fragments (all independent 16B loads)
    short8 A[16];
    #pragma unroll
    for (int k = 0; k < 16; ++k) A[k] = ap[k * 4];
    short8 B[3][16];
    #pragma unroll
    for (int g = 0; g < 3; ++g)
        #pragma unroll
        for (int k = 0; k < 16; ++k)
            B[g][k] = bp[g * 32768 + k * 4];

    // Hoist MX / h_old / bias loads (independent of the MFMA chain).
    float mxz[4], mxr[4], mxh[4], hold[4];
    #pragma unroll
    for (int q = 0; q < 4; ++q) {
        const float* mx = MXc + (long)(m0 + row + q) * N3 + u;
        mxz[q] = mx[0];
        mxr[q] = mx[UU];
        mxh[q] = mx[2 * UU];
        hold[q] = hf[(long)(m0 + row + q) * UU + u];
    }
    const float rbz = rbias[u];
    const float rbr = rbias[u + UU];
    const float rbh = rbias[u + 2 * UU];

    f32x4 az = {0.f,0.f,0.f,0.f}, ag = {0.f,0.f,0.f,0.f}, ah = {0.f,0.f,0.f,0.f};
    #pragma unroll
    for (int k = 0; k < 16; ++k) {
        az = __builtin_amdgcn_mfma_f32_16x16x32_bf16(A[k], B[0][k], az, 0, 0, 0);
        ag = __builtin_amdgcn_mfma_f32_16x16x32_bf16(A[k], B[1][k], ag, 0, 0, 0);
        ah = __builtin_amdgcn_mfma_f32_16x16x32_bf16(A[k], B[2][k], ah, 0, 0, 0);
    }

    #pragma unroll
    for (int q = 0; q < 4; ++q) {
        const int m = m0 + row + q;
        const float z = sigmoidf_(mxz[q] + az[q] + rbz);
        const float r = sigmoidf_(mxr[q] + ag[q] + rbr);
        const float cand = mxh[q] + r * (ah[q] + rbh);   // reset_after
        const float hh = fmaxf(cand, 0.0f);              // relu
        const float hn = z * hold[q] + (1.0f - z) * hh;
        hf_out[(long)m * UU + u] = hn;
        hbf_out[(long)m * UU + u] = __float2bfloat16(hn);
    }
}

extern "C" void kernel_launch(void* const* d_in, const int* in_sizes, int n_in,
                              void* d_out, int out_size, void* d_ws, size_t ws_size,
                              hipStream_t stream)
{
    const float* x     = (const float*)d_in[0];   // [256,192,512]
    const float* ker   = (const float*)d_in[1];   // [512,1536]
    const float* rker  = (const float*)d_in[2];   // [512,1536]
    const float* ibias = (const float*)d_in[3];   // [1536]
    const float* rbias = (const float*)d_in[4];   // [1536]
    float* out = (float*)d_out;                   // [256,512]

    char* ws = (char*)d_ws;
    float*          MX   = (float*)ws;                            // 12,582,912 B
    __hip_bfloat16* Xb   = (__hip_bfloat16*)(ws + 12582912);      //  2,097,152 B
    __hip_bfloat16* Kt   = (__hip_bfloat16*)(ws + 14680064);      //  1,572,864 B
    __hip_bfloat16* Rt   = (__hip_bfloat16*)(ws + 16252928);      //  1,572,864 B
    float*          hf0  = (float*)(ws + 17825792);               //    524,288 B
    __hip_bfloat16* hbf0 = (__hip_bfloat16*)(ws + 18350080);      //    262,144 B
    float*          hf1  = (float*)(ws + 18612224);               //    524,288 B
    __hip_bfloat16* hbf1 = (__hip_bfloat16*)(ws + 19136512);      //    262,144 B

    // Phase 0: weight transposes + x gather/convert
    transpose_bf16<<<dim3(48, 16), dim3(32, 8), 0, stream>>>(ker,  Kt, 512, 1536);
    transpose_bf16<<<dim3(48, 16), dim3(32, 8), 0, stream>>>(rker, Rt, 512, 1536);
    convert_x<<<512, 256, 0, stream>>>(x, Xb);

    // Phase 1: MX = Xsel @ kernel + input_bias
    gemm_mx<<<dim3(N3 / 64, 2048 / 64), 256, 0, stream>>>(Xb, Kt, ibias, MX);

    // Phase 2: step 0 is elementwise-only (h0 == 0); writes hf1/hbf1.
    gru_step0<<<dim3(BB * UU / 256), 256, 0, stream>>>(MX, rbias, hf1, hbf1);

    // Steps 1..7 (c odd reads hf1/hbf1)
    for (int c = 1; c < 8; ++c) {
        const __hip_bfloat16* hb_in = (c & 1) ? hbf1 : hbf0;
        const float*          hf_in = (c & 1) ? hf1 : hf0;
        float*          hf_o = (c == 7) ? out : ((c & 1) ? hf0 : hf1);
        __hip_bfloat16* hb_o = (c & 1) ? hbf0 : hbf1;
        gru_step<<<dim3(UU / 32, BB / 32), 256, 0, stream>>>(
            hb_in, hf_in, Rt, rbias, MX + (long)c * BB * N3, hf_o, hb_o);
    }
}